// Round 15
// baseline (54.834 us; speedup 1.0000x reference)
//
#include <hip/hip_runtime.h>
#include <hip/hip_bf16.h>

#define Nn 8192
#define Mm 1024
#define Dd 1024

typedef __attribute__((ext_vector_type(8))) short short8;
typedef __attribute__((ext_vector_type(4))) short short4v;
typedef __attribute__((ext_vector_type(4))) float f32x4;
typedef __attribute__((ext_vector_type(4))) unsigned uint4v;

typedef const __attribute__((address_space(1))) void* gas_p;
typedef __attribute__((address_space(3))) void* las_p;

// round-to-nearest-even fp32 -> bf16 (bit pattern as short)
__device__ __forceinline__ short f2bf(float f) {
  unsigned u = __builtin_bit_cast(unsigned, f);
  u += 0x7fffu + ((u >> 16) & 1u);
  return (short)(u >> 16);
}

// packed RNE fp32x2 -> bf16x2 (hardware cvt; R5/R7-passed)
__device__ __forceinline__ unsigned cvt2bf(float lo, float hi) {
  unsigned r;
  asm("v_cvt_pk_bf16_f32 %0, %1, %2" : "=v"(r) : "v"(lo), "v"(hi));
  return r;
}

// ---------------- kernel 1: B'[m,d] = bf16(u*w3 + w1); c[m] = u . w2  [R1-passed] ----------------
__global__ void prep_b_kernel(const float* __restrict__ u, const float* __restrict__ w,
                              short* __restrict__ Bp, float* __restrict__ cvec) {
  int m = blockIdx.x;      // 1024 blocks
  int t = threadIdx.x;     // 256 threads, 4 elems each
  float4 uv = ((const float4*)(u + (size_t)m * Dd))[t];
  float4 w1 = ((const float4*)(w))[t];
  float4 w2 = ((const float4*)(w + Dd))[t];
  float4 w3 = ((const float4*)(w + 2 * Dd))[t];
  float p = uv.x * w2.x + uv.y * w2.y + uv.z * w2.z + uv.w * w2.w;
  short4v o;
  o[0] = f2bf(fmaf(uv.x, w3.x, w1.x));
  o[1] = f2bf(fmaf(uv.y, w3.y, w1.y));
  o[2] = f2bf(fmaf(uv.z, w3.z, w1.z));
  o[3] = f2bf(fmaf(uv.w, w3.w, w1.w));
  *(short4v*)(Bp + (size_t)m * Dd + t * 4) = o;

#pragma unroll
  for (int off = 32; off > 0; off >>= 1) p += __shfl_down(p, off);
  __shared__ float sred[4];
  if ((t & 63) == 0) sred[t >> 6] = p;
  __syncthreads();
  if (t == 0) cvec[m] = sred[0] + sred[1] + sred[2] + sred[3];
}

// ---------------- kernel 2: fused GEMM  S = bf16(h) @ B'^T + c ----------------
// Tile 64x128 (BM x BN), BK=64, **128 thr = 2 waves, wave 64x64** (best
// FLOP-per-LDS-byte wave shape; R1-proven wave math with wr=0, wc=wid).
// Grid 1024 -> 4 blocks/CU (R14-proven convoy masking); LDS 24 KB single-buffer.
// Per-CU LDS traffic 3.6 MB (vs R14's 4.6) -- LDS-BW is the session-measured
// binding constraint.
// A: FUSED fp32->bf16 (kills conv_h's 9 us): thread t -> row t>>1, k-half t&1;
//    8x float4 loads (128B contiguous), cvt_pk, 4x swizzled ds_write_b128
//    (R5/R7-passed pattern family). A(kt+1) loads issued after the stage-sync
//    -> fly under compute (T14-lite).
// B: R0-passed gload_lds staging (8 rows x 128B, kc=(lane&7)^l8 pre-swizzle).
// Loop: R0-passed skeleton {stage; WRITE_A; sync; LOAD_A(kt+1); compute; sync}.
__global__ __launch_bounds__(128) void gemm_fused_kernel(
    const float* __restrict__ h,   // N x D fp32
    const short* __restrict__ B,   // M x D bf16 (B')
    const float* __restrict__ cvec,// M
    float* __restrict__ out)       // N x M fp32
{
  __shared__ __align__(16) short As[64 * 64];    //  8 KB
  __shared__ __align__(16) short Bs[128 * 64];   // 16 KB

  const int bid = blockIdx.x;
  // bijective XCD swizzle: 1024 blocks, 128/XCD; XCD x: brows [16x,16x+16), all 8 bcols
  const int swz  = (bid & 7) * 128 + (bid >> 3);
  const int brow = swz >> 3;   // 0..127 (64-row panel)
  const int bcol = swz & 7;    // 0..7   (128-col panel)

  const int tid  = threadIdx.x;  // 0..127
  const int lane = tid & 63;
  const int wid  = tid >> 6;     // 0..1

  // --- B staging (R0-passed): wave wid stages rows [wid*64,+64), 8 calls ---
  const int l8 = lane >> 3;
  const int kc = (lane & 7) ^ l8;          // pre-swizzled 16B-chunk index
  const short* Bg = B + (size_t)(bcol * 128 + wid * 64 + l8) * Dd + kc * 8;
  const int BsOff = (wid * 64) * 64;

  // --- A fused reg-staging: thread t -> row t>>1 (0..63), k-half t&1 (32 floats) ---
  const int arow  = tid >> 1;
  const int ahalf = tid & 1;
  const float* hg = h + (size_t)(brow * 64 + arow) * Dd + ahalf * 32;
  const int asw = (arow & 7) << 4;
  const int ab0 = arow * 128 + ((ahalf * 64 +  0) ^ asw);
  const int ab1 = arow * 128 + ((ahalf * 64 + 16) ^ asw);
  const int ab2 = arow * 128 + ((ahalf * 64 + 32) ^ asw);
  const int ab3 = arow * 128 + ((ahalf * 64 + 48) ^ asw);

  // --- fragment reads (R1-passed math; wr=0, wc=wid) ---
  const int arow0 = lane & 15;
  const int brow0 = wid * 64 + (lane & 15);
  const int kb = (lane >> 4) * 16;         // 16B chunk within 64B k-slice
  const int sw = (lane & 7) << 4;          // read-side XOR (row&7)<<4

  f32x4 acc[4][4] = {};
  float4 av0, av1, av2, av3, av4, av5, av6, av7;  // named regs (rule #20)

#define STAGE_B(kt) do { \
    const short* Bgk_ = Bg + (size_t)(kt) * 64; \
    _Pragma("unroll") \
    for (int j_ = 0; j_ < 8; ++j_) \
      __builtin_amdgcn_global_load_lds((gas_p)(Bgk_ + j_ * 8 * Dd), \
                                       (las_p)(&Bs[BsOff + j_ * 8 * 64]), 16, 0, 0); \
  } while (0)

#define LOAD_A(kt) do { \
    const float* ab_ = hg + (size_t)(kt) * 64; \
    av0 = *(const float4*)(ab_);      av1 = *(const float4*)(ab_ + 4); \
    av2 = *(const float4*)(ab_ + 8);  av3 = *(const float4*)(ab_ + 12); \
    av4 = *(const float4*)(ab_ + 16); av5 = *(const float4*)(ab_ + 20); \
    av6 = *(const float4*)(ab_ + 24); av7 = *(const float4*)(ab_ + 28); \
  } while (0)

#define WRITE_A() do { \
    uint4v q_; \
    q_[0] = cvt2bf(av0.x, av0.y); q_[1] = cvt2bf(av0.z, av0.w); \
    q_[2] = cvt2bf(av1.x, av1.y); q_[3] = cvt2bf(av1.z, av1.w); \
    *(uint4v*)((char*)As + ab0) = q_; \
    q_[0] = cvt2bf(av2.x, av2.y); q_[1] = cvt2bf(av2.z, av2.w); \
    q_[2] = cvt2bf(av3.x, av3.y); q_[3] = cvt2bf(av3.z, av3.w); \
    *(uint4v*)((char*)As + ab1) = q_; \
    q_[0] = cvt2bf(av4.x, av4.y); q_[1] = cvt2bf(av4.z, av4.w); \
    q_[2] = cvt2bf(av5.x, av5.y); q_[3] = cvt2bf(av5.z, av5.w); \
    *(uint4v*)((char*)As + ab2) = q_; \
    q_[0] = cvt2bf(av6.x, av6.y); q_[1] = cvt2bf(av6.z, av6.w); \
    q_[2] = cvt2bf(av7.x, av7.y); q_[3] = cvt2bf(av7.z, av7.w); \
    *(uint4v*)((char*)As + ab3) = q_; \
  } while (0)

  const int NT = Dd / 64;  // 16 K-tiles

  LOAD_A(0);   // prologue

#pragma unroll 1
  for (int kt = 0; kt < NT; ++kt) {
    STAGE_B(kt);          // async B gloads
    WRITE_A();            // cvt (waits A regs) + 4 swizzled ds_write_b128
    __syncthreads();      // drains: B staged + A writes visible
    if (kt + 1 < NT) LOAD_A(kt + 1);   // flies under compute
    // ---- compute (R1-passed math) ----
#pragma unroll
    for (int kk = 0; kk < 2; ++kk) {
      short8 af[4], bfr[4];
      const int koff = kk * 64 + kb;
#pragma unroll
      for (int i = 0; i < 4; ++i) {
        af[i]  = *(const short8*)((const char*)As + ((arow0 + i * 16) * 128 + (koff ^ sw)));
        bfr[i] = *(const short8*)((const char*)Bs + ((brow0 + i * 16) * 128 + (koff ^ sw)));
      }
#pragma unroll
      for (int i = 0; i < 4; ++i)
#pragma unroll
        for (int j = 0; j < 4; ++j)
          acc[i][j] = __builtin_amdgcn_mfma_f32_16x16x32_bf16(af[i], bfr[j], acc[i][j], 0, 0, 0);
    }
    __syncthreads();      // all reads retired before next overwrite
  }
#undef STAGE_B
#undef LOAD_A
#undef WRITE_A

  // --- epilogue: S[n,m] = acc + c[m] (R1-passed mapping; wr=0, wc=wid) ---
  const int n0 = brow * 64 + (lane >> 4) * 4;
  const int m0 = bcol * 128 + wid * 64 + (lane & 15);
#pragma unroll
  for (int j = 0; j < 4; ++j) {
    const float cm = cvec[m0 + j * 16];
#pragma unroll
    for (int i = 0; i < 4; ++i) {
      float* op = out + (size_t)(n0 + i * 16) * Mm + m0 + j * 16;
#pragma unroll
      for (int r = 0; r < 4; ++r)
        op[(size_t)r * Mm] = acc[i][j][r] + cm;
    }
  }
}

extern "C" void kernel_launch(void* const* d_in, const int* in_sizes, int n_in,
                              void* d_out, int out_size, void* d_ws, size_t ws_size,
                              hipStream_t stream) {
  const float* h = (const float*)d_in[0];
  const float* u = (const float*)d_in[1];
  const float* w = (const float*)d_in[2];
  float* out = (float*)d_out;

  // workspace layout: B' bf16 (2MB) | c fp32 (4KB)
  short* Bp  = (short*)d_ws;
  float* cvec = (float*)(Bp + (size_t)Mm * Dd);

  prep_b_kernel<<<Mm, 256, 0, stream>>>(u, w, Bp, cvec);
  gemm_fused_kernel<<<(Nn / 64) * (Mm / 128), 128, 0, stream>>>(h, Bp, cvec, out);
}